// Round 6
// baseline (360.462 us; speedup 1.0000x reference)
//
#include <hip/hip_runtime.h>
#include <hip/hip_bf16.h>
#include <cstdint>

#define BATCH  2
#define SEQ    2048
#define DMODEL 1024
#define NH     16
#define DH     64

typedef short bf16x8 __attribute__((ext_vector_type(8)));
typedef float f32x4  __attribute__((ext_vector_type(4)));
typedef unsigned short u16;

#define MFMA16(a, b, c) __builtin_amdgcn_mfma_f32_16x16x32_bf16((a), (b), (c), 0, 0, 0)

static __device__ __forceinline__ u16 f2bf(float f) {
  union { float f; unsigned int i; } u; u.f = f;
  unsigned int r = u.i + 0x7FFFu + ((u.i >> 16) & 1u);  // round-nearest-even
  return (u16)(r >> 16);
}

// ---------------- x fp32 -> bf16 ----------------
__global__ __launch_bounds__(256) void convert_x_kernel(const float* __restrict__ X,
                                                        u16* __restrict__ Xb) {
  int idx = (blockIdx.x * 256 + threadIdx.x) * 8;
  float4 a = *reinterpret_cast<const float4*>(X + idx);
  float4 b = *reinterpret_cast<const float4*>(X + idx + 4);
  union { bf16x8 v; u16 u[8]; } pk;
  pk.u[0]=f2bf(a.x); pk.u[1]=f2bf(a.y); pk.u[2]=f2bf(a.z); pk.u[3]=f2bf(a.w);
  pk.u[4]=f2bf(b.x); pk.u[5]=f2bf(b.y); pk.u[6]=f2bf(b.z); pk.u[7]=f2bf(b.w);
  *reinterpret_cast<bf16x8*>(Xb + idx) = pk.v;
}

// ---------------- W [k][n] fp32 -> Wt [n][k] bf16 ----------------
__global__ __launch_bounds__(256) void transpose_w_kernel(const float* __restrict__ W0,
                                                          const float* __restrict__ W1,
                                                          const float* __restrict__ W2,
                                                          u16* __restrict__ Wt) {
  const float* W = (blockIdx.z == 0) ? W0 : (blockIdx.z == 1) ? W1 : W2;
  u16* out = Wt + (size_t)blockIdx.z * DMODEL * DMODEL;
  __shared__ float T[32][33];
  const int t = threadIdx.x;
  const int k0 = blockIdx.x * 32, n0 = blockIdx.y * 32;
  {
    int r = t >> 3, c = (t & 7) * 4;
    float4 v = *reinterpret_cast<const float4*>(W + (size_t)(k0 + r) * DMODEL + n0 + c);
    T[r][c] = v.x; T[r][c+1] = v.y; T[r][c+2] = v.z; T[r][c+3] = v.w;
  }
  __syncthreads();
  {
    int n = t >> 3, k = (t & 7) * 4;
    union { unsigned long long ll; u16 u[4]; } pk;
    pk.u[0] = f2bf(T[k][n]);   pk.u[1] = f2bf(T[k+1][n]);
    pk.u[2] = f2bf(T[k+2][n]); pk.u[3] = f2bf(T[k+3][n]);
    *reinterpret_cast<unsigned long long*>(out + (size_t)(n0 + n) * DMODEL + k0 + k) = pk.ll;
  }
}

// ---------------- QKV GEMM: Y[b,h,s,dh](bf16) = Xb[bs][k] * Wt[n][k]^T ----------------
__global__ __launch_bounds__(256) void qkv_mfma_kernel(const u16* __restrict__ Xb,
                                                       const u16* __restrict__ Wt,
                                                       u16* __restrict__ Y) {
  __shared__ u16 As[128 * 64];
  __shared__ u16 Bs[128 * 64];
  char* Ab = (char*)As; char* Bb = (char*)Bs;
  const int t = threadIdx.x;
  const int lane = t & 63;
  const int w = t >> 6;
  const int wr = w >> 1, wc = w & 1;
  const int l15 = lane & 15, lg = lane >> 4;
  const int row0 = blockIdx.x * 128;
  const int col0 = blockIdx.y * 128;
  const int z = blockIdx.z;
  const u16* Wz = Wt + (size_t)z * DMODEL * DMODEL;
  u16* Yz = Y + (size_t)z * ((size_t)BATCH * SEQ * DMODEL);

  f32x4 acc[4][4];
  #pragma unroll
  for (int mt = 0; mt < 4; ++mt)
    #pragma unroll
    for (int nt = 0; nt < 4; ++nt)
      acc[mt][nt] = (f32x4){0.f, 0.f, 0.f, 0.f};

  const int slot = t & 7;
  for (int k0 = 0; k0 < DMODEL; k0 += 64) {
    __syncthreads();
    #pragma unroll
    for (int r = 0; r < 4; ++r) {
      int row = r * 32 + (t >> 3);
      bf16x8 av = *reinterpret_cast<const bf16x8*>(Xb + (size_t)(row0 + row) * DMODEL + k0 + slot * 8);
      bf16x8 bv = *reinterpret_cast<const bf16x8*>(Wz + (size_t)(col0 + row) * DMODEL + k0 + slot * 8);
      int off = row * 128 + ((slot * 16) ^ ((row & 7) << 4));
      *reinterpret_cast<bf16x8*>(Ab + off) = av;
      *reinterpret_cast<bf16x8*>(Bb + off) = bv;
    }
    __syncthreads();
    #pragma unroll
    for (int c = 0; c < 2; ++c) {
      bf16x8 am[4], bn[4];
      int kof = c * 64 + lg * 16;
      #pragma unroll
      for (int mt = 0; mt < 4; ++mt) {
        int row = wr * 64 + mt * 16 + l15;
        am[mt] = *reinterpret_cast<const bf16x8*>(Ab + row * 128 + (kof ^ ((row & 7) << 4)));
      }
      #pragma unroll
      for (int nt = 0; nt < 4; ++nt) {
        int row = wc * 64 + nt * 16 + l15;
        bn[nt] = *reinterpret_cast<const bf16x8*>(Bb + row * 128 + (kof ^ ((row & 7) << 4)));
      }
      #pragma unroll
      for (int mt = 0; mt < 4; ++mt)
        #pragma unroll
        for (int nt = 0; nt < 4; ++nt)
          acc[mt][nt] = MFMA16(am[mt], bn[nt], acc[mt][nt]);
    }
  }

  #pragma unroll
  for (int mt = 0; mt < 4; ++mt) {
    #pragma unroll
    for (int i = 0; i < 4; ++i) {
      int bs = row0 + wr * 64 + mt * 16 + lg * 4 + i;
      int b = bs >> 11, s = bs & (SEQ - 1);
      #pragma unroll
      for (int nt = 0; nt < 4; ++nt) {
        int d = col0 + wc * 64 + nt * 16 + l15;
        int h = d >> 6, dd = d & (DH - 1);
        size_t off = (((size_t)b * NH + h) * SEQ + s) * DH + dd;
        Yz[off] = f2bf(acc[mt][nt][i]);
      }
    }
  }
}

// ---------------- V [b,h,s,dh] -> Vt [b,h,dh,s] ----------------
__global__ __launch_bounds__(256) void transpose_v_kernel(const u16* __restrict__ V,
                                                          u16* __restrict__ Vt) {
  __shared__ u16 L[64][72];
  const int sb = blockIdx.x, h = blockIdx.y, b = blockIdx.z;
  const size_t hin  = ((size_t)b * NH + h) * (size_t)SEQ * DH;
  const size_t hout = ((size_t)b * NH + h) * (size_t)DH * SEQ;
  const int s0 = sb * 64;
  const int t = threadIdx.x;
  const int r = t >> 3, c = t & 7;
  #pragma unroll
  for (int it = 0; it < 2; ++it) {
    int row = r + it * 32;
    bf16x8 v = *reinterpret_cast<const bf16x8*>(V + hin + (size_t)(s0 + row) * DH + c * 8);
    *reinterpret_cast<bf16x8*>(&L[row][c * 8]) = v;
  }
  __syncthreads();
  #pragma unroll
  for (int it = 0; it < 2; ++it) {
    int d = r + it * 32;
    union { bf16x8 v; u16 u[8]; } pk;
    #pragma unroll
    for (int j = 0; j < 8; ++j) pk.u[j] = L[c * 8 + j][d];
    *reinterpret_cast<bf16x8*>(Vt + hout + (size_t)d * SEQ + s0 + c * 8) = pk.v;
  }
}

// load tile (k0) K+V from global into registers
#define LOAD_KV(kreg, vreg, k0)                                                             \
  {                                                                                         \
    _Pragma("unroll")                                                                       \
    for (int it = 0; it < 4; ++it) {                                                        \
      int idx = it * 256 + t;                                                               \
      int row = idx >> 3, sl = idx & 7;                                                     \
      kreg[it] = *reinterpret_cast<const bf16x8*>(Kw + hq + (size_t)((k0) + row) * DH + sl * 8); \
      int d = idx >> 4, kk = idx & 15;                                                      \
      vreg[it] = *reinterpret_cast<const bf16x8*>(Vt + hv + (size_t)d * SEQ + (k0) + kk * 8);    \
    }                                                                                       \
  }

// write register tile into LDS (K swizzled; V slot-permuted + swizzled)
#define WRITE_KV(kreg, vreg)                                                                \
  {                                                                                         \
    _Pragma("unroll")                                                                       \
    for (int it = 0; it < 4; ++it) {                                                        \
      int idx = it * 256 + t;                                                               \
      int row = idx >> 3, sl = idx & 7;                                                     \
      *reinterpret_cast<bf16x8*>(Kb + row * 128 + ((sl * 16) ^ ((row & 7) << 4))) = kreg[it];    \
      int d = idx >> 4, kk = idx & 15;                                                      \
      union { bf16x8 vv; unsigned long long q[2]; } uu;                                     \
      uu.vv = vreg[it];                                                                     \
      int kc = kk >> 2, g2 = kk & 3;                                                        \
      int t1b = kc * 64 + ((g2 & 1) * 32) + ((g2 >> 1) * 8);                                \
      int swz = (d & 7) << 4;                                                               \
      *reinterpret_cast<unsigned long long*>(Vb + d * 256 + (t1b ^ swz)) = uu.q[0];         \
      *reinterpret_cast<unsigned long long*>(Vb + d * 256 + ((t1b + 16) ^ swz)) = uu.q[1];  \
    }                                                                                       \
  }

// ---------------- Flash attention: paired q-tiles + swapped QK + prefetch ----------------
// 512 blocks: wgid&7 = XCD slot; each XCD owns 4 head-groups; 16 pair-blocks per head.
__global__ __launch_bounds__(256) void flash_mfma4_kernel(const u16* __restrict__ Qw,
                                                          const u16* __restrict__ Kw,
                                                          const u16* __restrict__ Vt,
                                                          float* __restrict__ Out) {
  __shared__ u16 Ks[128 * 64];        // row=key(128) x d(64), XOR-swizzled
  __shared__ u16 Vs[64 * 128];        // row=d(64) x slot(128), slot-permuted + swizzled
  char* Kb = (char*)Ks; char* Vb = (char*)Vs;

  const int wgid = blockIdx.x;
  const int x = wgid & 7;             // XCD slot
  const int r = wgid >> 3;            // 0..63
  const int pi = r & 15;              // pair index 0..15
  const int g = x * 4 + (r >> 4);     // head-group 0..31
  const int b = g >> 4, h = g & 15;

  const int t = threadIdx.x, lane = t & 63, w = t >> 6;
  const int l15 = lane & 15, lg = lane >> 4;
  const size_t hq = ((size_t)b * NH + h) * (size_t)SEQ * DH;
  const size_t hv = ((size_t)b * NH + h) * (size_t)DH * SEQ;

  #pragma unroll 1
  for (int half = 0; half < 2; ++half) {
    const int qt = half ? (31 - pi) : pi;
    const int q0 = qt * 64;
    const int nkv = (qt >> 1) + 1;

    // Q fragments: B-operand of swapped QK. Lane holds Q[q=q0+w*16+l15][d=lg*8+j]
    bf16x8 qf0, qf1;
    {
      const int qrow = q0 + w * 16 + l15;
      const u16* qp = Qw + hq + (size_t)qrow * DH + lg * 8;
      qf0 = *reinterpret_cast<const bf16x8*>(qp);
      qf1 = *reinterpret_cast<const bf16x8*>(qp + 32);
    }

    f32x4 o[4];
    #pragma unroll
    for (int dt = 0; dt < 4; ++dt) o[dt] = (f32x4){0.f, 0.f, 0.f, 0.f};
    float m_ = -1e30f, l_ = 0.f;      // stats for query q0 + w*16 + l15

    auto compute_tile = [&](int kb) {
      const int k0 = kb * 128;
      const bool diag = (kb == nkv - 1);
      const int qmaxw = q0 + w * 16 + 15;
      const int ktlim = diag ? (((qmaxw - k0) >> 4) + 1) : 8;
      const int kcmax = diag ? ((ktlim + 1) >> 1) : 4;

      // swapped QK^T: lane holds P[q=l15][key=kt*16+lg*4+i]
      float p[8][4];
      #pragma unroll
      for (int kt = 0; kt < 8; ++kt) {
        if (kt < ktlim) {
          int row = kt * 16 + l15;
          int sw = (row & 7) << 4;
          bf16x8 kf0 = *reinterpret_cast<const bf16x8*>(Kb + row * 128 + ((lg * 16) ^ sw));
          bf16x8 kf1 = *reinterpret_cast<const bf16x8*>(Kb + row * 128 + ((64 + lg * 16) ^ sw));
          f32x4 sa = (f32x4){0.f, 0.f, 0.f, 0.f};
          sa = MFMA16(kf0, qf0, sa);
          sa = MFMA16(kf1, qf1, sa);
          #pragma unroll
          for (int i = 0; i < 4; ++i) {
            float sv = sa[i] * 0.125f;
            if (diag) {
              int key = k0 + kt * 16 + lg * 4 + i;
              int q   = q0 + w * 16 + l15;
              if (key > q) sv = -1e30f;
            }
            p[kt][i] = sv;
          }
        } else {
          p[kt][0] = -1e30f; p[kt][1] = -1e30f; p[kt][2] = -1e30f; p[kt][3] = -1e30f;
        }
      }

      // online softmax: per-lane row, reduce across lg groups (xor 16, 32)
      float mloc = p[0][0];
      #pragma unroll
      for (int kt = 0; kt < 8; ++kt)
        #pragma unroll
        for (int i = 0; i < 4; ++i) mloc = fmaxf(mloc, p[kt][i]);
      mloc = fmaxf(mloc, __shfl_xor(mloc, 16));
      mloc = fmaxf(mloc, __shfl_xor(mloc, 32));
      float mn = fmaxf(m_, mloc);
      float scale = __expf(m_ - mn);
      m_ = mn;

      // fused exp + sum + bf16 pack
      float ps = 0.f;
      bf16x8 pa[4];
      #pragma unroll
      for (int kc = 0; kc < 4; ++kc) {
        union { bf16x8 v; u16 u[8]; } pk;
        #pragma unroll
        for (int i = 0; i < 4; ++i) {
          float e0 = __expf(p[2 * kc][i] - mn);
          float e1 = __expf(p[2 * kc + 1][i] - mn);
          ps += e0 + e1;
          pk.u[i]     = f2bf(e0);
          pk.u[4 + i] = f2bf(e1);
        }
        pa[kc] = pk.v;
      }
      ps += __shfl_xor(ps, 16);
      ps += __shfl_xor(ps, 32);
      l_ = l_ * scale + ps;

      // rescale o
      #pragma unroll
      for (int i = 0; i < 4; ++i) {
        float sci = __shfl(scale, (lane & 48) + lg * 4 + i);
        #pragma unroll
        for (int dt = 0; dt < 4; ++dt) o[dt][i] *= sci;
      }

      // PV
      #pragma unroll
      for (int kc = 0; kc < 4; ++kc) {
        if (kc >= kcmax) break;
        #pragma unroll
        for (int dt = 0; dt < 4; ++dt) {
          int vrow = dt * 16 + l15;
          bf16x8 vbf = *reinterpret_cast<const bf16x8*>(Vb + vrow * 256 + ((kc * 64 + lg * 16) ^ ((vrow & 7) << 4)));
          o[dt] = MFMA16(pa[kc], vbf, o[dt]);
        }
      }
    };

    // prefetched K/V staging: double register sets, single LDS buffer
    bf16x8 kA[4], vA[4], kB[4], vB[4];
    LOAD_KV(kA, vA, 0);
    int kb = 0;
    for (;;) {
      __syncthreads();
      WRITE_KV(kA, vA);
      if (kb + 1 < nkv) LOAD_KV(kB, vB, (kb + 1) * 128);
      __syncthreads();
      compute_tile(kb);
      if (++kb == nkv) break;
      __syncthreads();
      WRITE_KV(kB, vB);
      if (kb + 1 < nkv) LOAD_KV(kA, vA, (kb + 1) * 128);
      __syncthreads();
      compute_tile(kb);
      if (++kb == nkv) break;
    }

    // epilogue: o[dt][i] is query q0+w*16+lg*4+i, d = dt*16+l15
    #pragma unroll
    for (int i = 0; i < 4; ++i) {
      float li = __shfl(l_, (lane & 48) + lg * 4 + i);
      float inv = 1.f / li;
      int q = q0 + w * 16 + lg * 4 + i;
      float* op = Out + ((size_t)b * SEQ + q) * DMODEL + h * DH + l15;
      #pragma unroll
      for (int dt = 0; dt < 4; ++dt) op[dt * 16] = o[dt][i] * inv;
    }
  }
}

extern "C" void kernel_launch(void* const* d_in, const int* in_sizes, int n_in,
                              void* d_out, int out_size, void* d_ws, size_t ws_size,
                              hipStream_t stream) {
  const float* x  = (const float*)d_in[0];
  const float* Wq = (const float*)d_in[1];
  const float* Wk = (const float*)d_in[2];
  const float* Wv = (const float*)d_in[3];
  float* out = (float*)d_out;

  u16* ws  = (u16*)d_ws;
  u16* qkv = ws;                         // 3 x 4,194,304 bf16  (24 MB)
  u16* xb  = ws + 12582912;              // 4,194,304 bf16      ( 8 MB)
  u16* wt  = ws + 16777216;              // 3 x 1,048,576 bf16  ( 6 MB)
  u16* vt  = ws + 19922944;              // 4,194,304 bf16      ( 8 MB)

  convert_x_kernel<<<2048, 256, 0, stream>>>(x, xb);
  transpose_w_kernel<<<dim3(32, 32, 3), 256, 0, stream>>>(Wq, Wk, Wv, wt);
  qkv_mfma_kernel<<<dim3(32, 8, 3), 256, 0, stream>>>(xb, wt, qkv);
  transpose_v_kernel<<<dim3(32, NH, BATCH), 256, 0, stream>>>(qkv + 8388608, vt);
  flash_mfma4_kernel<<<512, 256, 0, stream>>>(qkv, qkv + 4194304, vt, out);
}

// Round 7
// 122.305 us; speedup vs baseline: 2.9472x; 2.9472x over previous
//
#include <hip/hip_runtime.h>
#include <hip/hip_bf16.h>
#include <cstdint>

#define BATCH  2
#define SEQ    2048
#define DMODEL 1024
#define NH     16
#define DH     64

typedef short bf16x8 __attribute__((ext_vector_type(8)));
typedef float f32x4  __attribute__((ext_vector_type(4)));
typedef unsigned short u16;

#define MFMA16(a, b, c) __builtin_amdgcn_mfma_f32_16x16x32_bf16((a), (b), (c), 0, 0, 0)

static __device__ __forceinline__ u16 f2bf(float f) {
  union { float f; unsigned int i; } u; u.f = f;
  unsigned int r = u.i + 0x7FFFu + ((u.i >> 16) & 1u);  // round-nearest-even
  return (u16)(r >> 16);
}

// ---------------- x fp32 -> bf16 ----------------
__global__ __launch_bounds__(256) void convert_x_kernel(const float* __restrict__ X,
                                                        u16* __restrict__ Xb) {
  int idx = (blockIdx.x * 256 + threadIdx.x) * 8;
  float4 a = *reinterpret_cast<const float4*>(X + idx);
  float4 b = *reinterpret_cast<const float4*>(X + idx + 4);
  union { bf16x8 v; u16 u[8]; } pk;
  pk.u[0]=f2bf(a.x); pk.u[1]=f2bf(a.y); pk.u[2]=f2bf(a.z); pk.u[3]=f2bf(a.w);
  pk.u[4]=f2bf(b.x); pk.u[5]=f2bf(b.y); pk.u[6]=f2bf(b.z); pk.u[7]=f2bf(b.w);
  *reinterpret_cast<bf16x8*>(Xb + idx) = pk.v;
}

// ---------------- W [k][n] fp32 -> Wt [n][k] bf16 ----------------
__global__ __launch_bounds__(256) void transpose_w_kernel(const float* __restrict__ W0,
                                                          const float* __restrict__ W1,
                                                          const float* __restrict__ W2,
                                                          u16* __restrict__ Wt) {
  const float* W = (blockIdx.z == 0) ? W0 : (blockIdx.z == 1) ? W1 : W2;
  u16* out = Wt + (size_t)blockIdx.z * DMODEL * DMODEL;
  __shared__ float T[32][33];
  const int t = threadIdx.x;
  const int k0 = blockIdx.x * 32, n0 = blockIdx.y * 32;
  {
    int r = t >> 3, c = (t & 7) * 4;
    float4 v = *reinterpret_cast<const float4*>(W + (size_t)(k0 + r) * DMODEL + n0 + c);
    T[r][c] = v.x; T[r][c+1] = v.y; T[r][c+2] = v.z; T[r][c+3] = v.w;
  }
  __syncthreads();
  {
    int n = t >> 3, k = (t & 7) * 4;
    union { unsigned long long ll; u16 u[4]; } pk;
    pk.u[0] = f2bf(T[k][n]);   pk.u[1] = f2bf(T[k+1][n]);
    pk.u[2] = f2bf(T[k+2][n]); pk.u[3] = f2bf(T[k+3][n]);
    *reinterpret_cast<unsigned long long*>(out + (size_t)(n0 + n) * DMODEL + k0 + k) = pk.ll;
  }
}

// ---------------- QKV GEMM: Y[b,h,s,dh](bf16) = Xb[bs][k] * Wt[n][k]^T ----------------
__global__ __launch_bounds__(256) void qkv_mfma_kernel(const u16* __restrict__ Xb,
                                                       const u16* __restrict__ Wt,
                                                       u16* __restrict__ Y) {
  __shared__ u16 As[128 * 64];
  __shared__ u16 Bs[128 * 64];
  char* Ab = (char*)As; char* Bb = (char*)Bs;
  const int t = threadIdx.x;
  const int lane = t & 63;
  const int w = t >> 6;
  const int wr = w >> 1, wc = w & 1;
  const int l15 = lane & 15, lg = lane >> 4;
  const int row0 = blockIdx.x * 128;
  const int col0 = blockIdx.y * 128;
  const int z = blockIdx.z;
  const u16* Wz = Wt + (size_t)z * DMODEL * DMODEL;
  u16* Yz = Y + (size_t)z * ((size_t)BATCH * SEQ * DMODEL);

  f32x4 acc[4][4];
  #pragma unroll
  for (int mt = 0; mt < 4; ++mt)
    #pragma unroll
    for (int nt = 0; nt < 4; ++nt)
      acc[mt][nt] = (f32x4){0.f, 0.f, 0.f, 0.f};

  const int slot = t & 7;
  for (int k0 = 0; k0 < DMODEL; k0 += 64) {
    __syncthreads();
    #pragma unroll
    for (int r = 0; r < 4; ++r) {
      int row = r * 32 + (t >> 3);
      bf16x8 av = *reinterpret_cast<const bf16x8*>(Xb + (size_t)(row0 + row) * DMODEL + k0 + slot * 8);
      bf16x8 bv = *reinterpret_cast<const bf16x8*>(Wz + (size_t)(col0 + row) * DMODEL + k0 + slot * 8);
      int off = row * 128 + ((slot * 16) ^ ((row & 7) << 4));
      *reinterpret_cast<bf16x8*>(Ab + off) = av;
      *reinterpret_cast<bf16x8*>(Bb + off) = bv;
    }
    __syncthreads();
    #pragma unroll
    for (int c = 0; c < 2; ++c) {
      bf16x8 am[4], bn[4];
      int kof = c * 64 + lg * 16;
      #pragma unroll
      for (int mt = 0; mt < 4; ++mt) {
        int row = wr * 64 + mt * 16 + l15;
        am[mt] = *reinterpret_cast<const bf16x8*>(Ab + row * 128 + (kof ^ ((row & 7) << 4)));
      }
      #pragma unroll
      for (int nt = 0; nt < 4; ++nt) {
        int row = wc * 64 + nt * 16 + l15;
        bn[nt] = *reinterpret_cast<const bf16x8*>(Bb + row * 128 + (kof ^ ((row & 7) << 4)));
      }
      #pragma unroll
      for (int mt = 0; mt < 4; ++mt)
        #pragma unroll
        for (int nt = 0; nt < 4; ++nt)
          acc[mt][nt] = MFMA16(am[mt], bn[nt], acc[mt][nt]);
    }
  }

  #pragma unroll
  for (int mt = 0; mt < 4; ++mt) {
    #pragma unroll
    for (int i = 0; i < 4; ++i) {
      int bs = row0 + wr * 64 + mt * 16 + lg * 4 + i;
      int b = bs >> 11, s = bs & (SEQ - 1);
      #pragma unroll
      for (int nt = 0; nt < 4; ++nt) {
        int d = col0 + wc * 64 + nt * 16 + l15;
        int h = d >> 6, dd = d & (DH - 1);
        size_t off = (((size_t)b * NH + h) * SEQ + s) * DH + dd;
        Yz[off] = f2bf(acc[mt][nt][i]);
      }
    }
  }
}

// ---------------- V [b,h,s,dh] -> Vt [b,h,dh,s] ----------------
__global__ __launch_bounds__(256) void transpose_v_kernel(const u16* __restrict__ V,
                                                          u16* __restrict__ Vt) {
  __shared__ u16 L[64][72];
  const int sb = blockIdx.x, h = blockIdx.y, b = blockIdx.z;
  const size_t hin  = ((size_t)b * NH + h) * (size_t)SEQ * DH;
  const size_t hout = ((size_t)b * NH + h) * (size_t)DH * SEQ;
  const int s0 = sb * 64;
  const int t = threadIdx.x;
  const int r = t >> 3, c = t & 7;
  #pragma unroll
  for (int it = 0; it < 2; ++it) {
    int row = r + it * 32;
    bf16x8 v = *reinterpret_cast<const bf16x8*>(V + hin + (size_t)(s0 + row) * DH + c * 8);
    *reinterpret_cast<bf16x8*>(&L[row][c * 8]) = v;
  }
  __syncthreads();
  #pragma unroll
  for (int it = 0; it < 2; ++it) {
    int d = r + it * 32;
    union { bf16x8 v; u16 u[8]; } pk;
    #pragma unroll
    for (int j = 0; j < 8; ++j) pk.u[j] = L[c * 8 + j][d];
    *reinterpret_cast<bf16x8*>(Vt + hout + (size_t)d * SEQ + s0 + c * 8) = pk.v;
  }
}

// ---------------- Flash attention: paired q-tiles, KVBLK=128 (R3 structure) ----------------
// Block: 256 thr (4 waves), processes q-tiles {pi, 31-pi} of 64 rows (16/wave).
__global__ __launch_bounds__(256) void flash_mfma2_kernel(const u16* __restrict__ Qw,
                                                          const u16* __restrict__ Kw,
                                                          const u16* __restrict__ Vt,
                                                          float* __restrict__ Out) {
  __shared__ u16 Ks[128 * 64];        // row=key(128) x d(64), swizzled
  __shared__ u16 Vs[64 * 128];        // row=d(64) x key(128), swizzled
  __shared__ u16 Pl[4][16 * 128];     // per-wave P, swizzled
  char* Kb = (char*)Ks; char* Vb = (char*)Vs;
  const int pi = blockIdx.x, h = blockIdx.y, b = blockIdx.z;
  const int t = threadIdx.x, lane = t & 63, w = t >> 6;
  const int l15 = lane & 15, lg = lane >> 4;
  char* Pb = (char*)Pl[w];
  const size_t hq = ((size_t)b * NH + h) * (size_t)SEQ * DH;
  const size_t hv = ((size_t)b * NH + h) * (size_t)DH * SEQ;

  #pragma unroll 1
  for (int half = 0; half < 2; ++half) {
    const int qt = half ? (31 - pi) : pi;
    const int q0 = qt * 64;
    const int nkv = (qt >> 1) + 1;
    const int qrow = q0 + w * 16 + l15;

    bf16x8 qf0, qf1;
    {
      const u16* qp = Qw + hq + (size_t)qrow * DH + lg * 8;
      qf0 = *reinterpret_cast<const bf16x8*>(qp);
      qf1 = *reinterpret_cast<const bf16x8*>(qp + 32);
    }

    f32x4 o[4];
    #pragma unroll
    for (int dt = 0; dt < 4; ++dt) o[dt] = (f32x4){0.f, 0.f, 0.f, 0.f};
    float m_[4], l_[4];
    #pragma unroll
    for (int i = 0; i < 4; ++i) { m_[i] = -1e30f; l_[i] = 0.f; }

    #pragma unroll 1
    for (int kb = 0; kb < nkv; ++kb) {
      const int k0 = kb * 128;
      __syncthreads();
      // stage K rows: 128 x 128B, swizzled
      #pragma unroll
      for (int it = 0; it < 4; ++it) {
        int idx = it * 256 + t;
        int row = idx >> 3, sl = idx & 7;
        bf16x8 kv = *reinterpret_cast<const bf16x8*>(Kw + hq + (size_t)(k0 + row) * DH + sl * 8);
        *reinterpret_cast<bf16x8*>(Kb + row * 128 + ((sl * 16) ^ ((row & 7) << 4))) = kv;
      }
      // stage Vt rows: 64 x 256B, swizzled
      #pragma unroll
      for (int it = 0; it < 4; ++it) {
        int idx = it * 256 + t;
        int row = idx >> 4, sl = idx & 15;
        bf16x8 vv = *reinterpret_cast<const bf16x8*>(Vt + hv + (size_t)row * SEQ + k0 + sl * 8);
        *reinterpret_cast<bf16x8*>(Vb + row * 256 + ((sl * 16) ^ ((row & 7) << 4))) = vv;
      }
      __syncthreads();

      const bool diag = (kb == nkv - 1);
      const int qmax = q0 + w * 16 + 15;
      const int ktlim = diag ? (((qmax - k0) >> 4) + 1) : 8;   // 1..8
      const int kcmax = diag ? ((ktlim + 1) >> 1) : 4;

      float s[8][4];
      __builtin_amdgcn_s_setprio(1);
      #pragma unroll
      for (int kt = 0; kt < 8; ++kt) {
        if (kt < ktlim) {
          int row = kt * 16 + l15;
          int sw = (row & 7) << 4;
          f32x4 sa = (f32x4){0.f, 0.f, 0.f, 0.f};
          bf16x8 kf0 = *reinterpret_cast<const bf16x8*>(Kb + row * 128 + ((lg * 16) ^ sw));
          bf16x8 kf1 = *reinterpret_cast<const bf16x8*>(Kb + row * 128 + ((64 + lg * 16) ^ sw));
          sa = MFMA16(qf0, kf0, sa);
          sa = MFMA16(qf1, kf1, sa);
          #pragma unroll
          for (int i = 0; i < 4; ++i) {
            float sv = sa[i] * 0.125f;
            if (diag) {
              int qr = q0 + w * 16 + lg * 4 + i;
              int kr = k0 + kt * 16 + l15;
              if (kr > qr) sv = -1e30f;
            }
            s[kt][i] = sv;
          }
        } else {
          s[kt][0] = -1e30f; s[kt][1] = -1e30f; s[kt][2] = -1e30f; s[kt][3] = -1e30f;
        }
      }
      __builtin_amdgcn_s_setprio(0);

      // online softmax across the 128-key tile
      #pragma unroll
      for (int i = 0; i < 4; ++i) {
        float mx = s[0][i];
        #pragma unroll
        for (int kt = 1; kt < 8; ++kt) mx = fmaxf(mx, s[kt][i]);
        mx = fmaxf(mx, __shfl_xor(mx, 1));
        mx = fmaxf(mx, __shfl_xor(mx, 2));
        mx = fmaxf(mx, __shfl_xor(mx, 4));
        mx = fmaxf(mx, __shfl_xor(mx, 8));
        float mn = fmaxf(m_[i], mx);
        float scale = __expf(m_[i] - mn);
        float ps = 0.f;
        #pragma unroll
        for (int kt = 0; kt < 8; ++kt) {
          float p = __expf(s[kt][i] - mn);
          s[kt][i] = p;
          ps += p;
        }
        ps += __shfl_xor(ps, 1); ps += __shfl_xor(ps, 2);
        ps += __shfl_xor(ps, 4); ps += __shfl_xor(ps, 8);
        l_[i] = l_[i] * scale + ps;
        m_[i] = mn;
        #pragma unroll
        for (int dt = 0; dt < 4; ++dt) o[dt][i] *= scale;
      }

      // P -> LDS (bf16 via native cast, wave-private, swizzled); masked entries exact 0
      #pragma unroll
      for (int kt = 0; kt < 8; ++kt) {
        #pragma unroll
        for (int i = 0; i < 4; ++i) {
          int q = lg * 4 + i;
          int off = q * 256 + ((kt * 32 + l15 * 2) ^ ((q & 7) << 4));
          *reinterpret_cast<__hip_bfloat16*>(Pb + off) = __float2bfloat16(s[kt][i]);
        }
      }

      // PV: o[dt] += P(16x32) x Vt(32x16) per 32-key chunk
      __builtin_amdgcn_s_setprio(1);
      #pragma unroll
      for (int kc = 0; kc < 4; ++kc) {
        if (kc >= kcmax) break;
        bf16x8 pa = *reinterpret_cast<const bf16x8*>(Pb + l15 * 256 + ((kc * 64 + lg * 16) ^ ((l15 & 7) << 4)));
        #pragma unroll
        for (int dt = 0; dt < 4; ++dt) {
          int vrow = dt * 16 + l15;
          bf16x8 vbf = *reinterpret_cast<const bf16x8*>(Vb + vrow * 256 + ((kc * 64 + lg * 16) ^ ((vrow & 7) << 4)));
          o[dt] = MFMA16(pa, vbf, o[dt]);
        }
      }
      __builtin_amdgcn_s_setprio(0);
    }

    #pragma unroll
    for (int i = 0; i < 4; ++i) {
      float inv = 1.f / l_[i];
      int q = q0 + w * 16 + lg * 4 + i;
      float* op = Out + ((size_t)b * SEQ + q) * DMODEL + h * DH + l15;
      #pragma unroll
      for (int dt = 0; dt < 4; ++dt) op[dt * 16] = o[dt][i] * inv;
    }
  }
}

extern "C" void kernel_launch(void* const* d_in, const int* in_sizes, int n_in,
                              void* d_out, int out_size, void* d_ws, size_t ws_size,
                              hipStream_t stream) {
  const float* x  = (const float*)d_in[0];
  const float* Wq = (const float*)d_in[1];
  const float* Wk = (const float*)d_in[2];
  const float* Wv = (const float*)d_in[3];
  float* out = (float*)d_out;

  u16* ws  = (u16*)d_ws;
  u16* qkv = ws;                         // 3 x 4,194,304 bf16  (24 MB)
  u16* xb  = ws + 12582912;              // 4,194,304 bf16      ( 8 MB)
  u16* wt  = ws + 16777216;              // 3 x 1,048,576 bf16  ( 6 MB)
  u16* vt  = ws + 19922944;              // 4,194,304 bf16      ( 8 MB)

  convert_x_kernel<<<2048, 256, 0, stream>>>(x, xb);
  transpose_w_kernel<<<dim3(32, 32, 3), 256, 0, stream>>>(Wq, Wk, Wv, wt);
  qkv_mfma_kernel<<<dim3(32, 8, 3), 256, 0, stream>>>(xb, wt, qkv);
  transpose_v_kernel<<<dim3(32, NH, BATCH), 256, 0, stream>>>(qkv + 8388608, vt);
  flash_mfma2_kernel<<<dim3(16, NH, BATCH), 256, 0, stream>>>(
      qkv, qkv + 4194304, vt, out);
}